// Round 1
// baseline (917.968 us; speedup 1.0000x reference)
//
#include <hip/hip_runtime.h>
#include <stdint.h>

#define NODE_NUM 8192
#define NN 8384        // total nodes per graph (8384 = 131*64)
#define CC 128         // channels
#define BB 2           // batch
#define EE 262144      // edges per graph (2^18)
#define CAP 128        // global bucket stride per (node,kind)
#define CAP2 120       // LDS bucket capacity (max degree ~60)
#define P_B 131        // partitions per batch, 64 nodes each
#define CAPP 4096      // partition buffer capacity (expected ~2000)
#define FILLB 256      // phase-0 fill blocks (256 * 2048 = 2^19 edges)
#define NTASK (BB * NN)

// Shared memory union: fill phase (~9.8KB) vs bucket phase (~31KB).
// 31KB -> 5 blocks/CU by LDS; VGPR (<=128 via launch_bounds) -> 4 blocks/CU.
union SMem {
  struct {
    unsigned int sEdge[2048];
    int sCnt[P_B];
    int sOff[P_B + 1];
    int sBase[P_B];
  } f;
  struct {
    unsigned int sIn[32 * CAP2];
    unsigned int sIt[32 * CAP2];
    int sC[64];                    // [0..31] intra, [32..63] inter
  } k;
};

__device__ __forceinline__ unsigned int f2bf_u(float f) {
  unsigned int u = __float_as_uint(f);
  return (u + 0x7FFFu + ((u >> 16) & 1u)) >> 16;
}
__device__ __forceinline__ float bf2f(unsigned int u) {
  return __uint_as_float(u << 16);
}

// Device-scope grid barrier (all blocks co-resident by construction).
// Release: every thread fences (flush own stores device-wide, per-XCD L2
// is not coherent) -> block barrier -> thread0 arrives with agent atomic.
// Acquire: trailing fence invalidates stale L1/L2 lines.
__device__ __forceinline__ void grid_barrier(int* bar, int target) {
  __threadfence();
  __syncthreads();
  if (threadIdx.x == 0) {
    int old = __hip_atomic_fetch_add(bar, 1, __ATOMIC_RELAXED, __HIP_MEMORY_SCOPE_AGENT);
    if (old + 1 < target) {
      while (__hip_atomic_fetch_add(bar, 0, __ATOMIC_RELAXED, __HIP_MEMORY_SCOPE_AGENT) < target)
        __builtin_amdgcn_s_sleep(4);
    }
  }
  __syncthreads();
  __threadfence();
}

// ---- phase 0a: LDS-segmented edge partitioning (one 2048-edge chunk) ----
__device__ __forceinline__ void do_fill(int blk, int tid, const int* __restrict__ ei,
                                        int* __restrict__ partCur,
                                        unsigned int* __restrict__ partBuf, SMem& sm) {
  int b = blk >> 7;                        // 128 blocks per batch
  int e0 = (blk & 127) * 2048;
  const int* eb = ei + b * 2 * EE;
  for (int i = tid; i < P_B; i += 256) sm.f.sCnt[i] = 0;
  __syncthreads();
  const int4* s4 = (const int4*)(eb + e0 + tid * 8);
  const int4* d4 = (const int4*)(eb + EE + e0 + tid * 8);
  int4 sa = s4[0], sb_ = s4[1], da = d4[0], db_ = d4[1];
  int srcs[8] = {sa.x, sa.y, sa.z, sa.w, sb_.x, sb_.y, sb_.z, sb_.w};
  int dsts[8] = {da.x, da.y, da.z, da.w, db_.x, db_.y, db_.z, db_.w};
  unsigned int cache[8];
#pragma unroll
  for (int k = 0; k < 8; ++k) {
    int src = srcs[k], dst = dsts[k];
    if ((unsigned)src >= NN || (unsigned)dst >= NN) { cache[k] = 0xFFFFFFFFu; continue; }
    int p = dst >> 6;
    cache[k] = ((unsigned)p << 20) | ((unsigned)(dst & 63) << 14) | (unsigned)src;
    atomicAdd(&sm.f.sCnt[p], 1);
  }
  __syncthreads();
  if (tid == 0) {                          // serial prefix over 131 entries
    int acc = 0;
    for (int i = 0; i < P_B; ++i) { sm.f.sOff[i] = acc; acc += sm.f.sCnt[i]; }
    sm.f.sOff[P_B] = acc;
  }
  __syncthreads();
  if (tid < P_B) sm.f.sBase[tid] = atomicAdd(&partCur[b * P_B + tid], sm.f.sCnt[tid]);
  __syncthreads();
  if (tid < P_B) sm.f.sCnt[tid] = 0;       // reuse as placement cursor
  __syncthreads();
#pragma unroll
  for (int k = 0; k < 8; ++k) {
    unsigned int v = cache[k];
    if (v == 0xFFFFFFFFu) continue;
    int p = v >> 20;
    int pos = atomicAdd(&sm.f.sCnt[p], 1);
    sm.f.sEdge[sm.f.sOff[p] + pos] = v;
  }
  __syncthreads();
  int total = sm.f.sOff[P_B];
  for (int i = tid; i < total; i += 256) {
    unsigned int v = sm.f.sEdge[i];
    int p = v >> 20;
    int idx = (i - sm.f.sOff[p]) + sm.f.sBase[p];
    if (idx < CAPP)
      partBuf[(size_t)(b * P_B + p) * CAPP + idx] = v & 0xFFFFFu;  // off|src
  }
}

// ---- phase 0b: bf16-pack x + layer-1 projections (1 wave/node) ----
__device__ __forceinline__ void node_init(int wid, int lane,
    const float* __restrict__ x, unsigned int* __restrict__ xb,
    const float* __restrict__ Wi_s, const float* __restrict__ Wj_s,
    const float* __restrict__ Wi_t, const float* __restrict__ Wj_t,
    float* __restrict__ pi, float2* __restrict__ pjn) {
  int n = wid % NN;
  bool is_s = (n < NODE_NUM);
  const float* wi = is_s ? Wi_s : Wi_t;
  const float* wj = is_s ? Wj_s : Wj_t;
  size_t oi = (size_t)wid * (CC / 2) + lane;
  float2 hv = ((const float2*)x)[oi];
  xb[oi] = (f2bf_u(hv.y) << 16) | f2bf_u(hv.x);
  float2 wiv = *(const float2*)(wi + lane * 2);
  float2 wjv = *(const float2*)(wj + lane * 2);
  float a = hv.x * wiv.x + hv.y * wiv.y;
  float c = hv.x * wjv.x + hv.y * wjv.y;
#pragma unroll
  for (int o = 32; o > 0; o >>= 1) {
    a += __shfl_xor(a, o, 64);
    c += __shfl_xor(c, o, 64);
  }
  if (lane == 0) { pi[wid] = a; pjn[wid].x = c; }
}

// ---- phase 1: per-half-partition (32 nodes) bucket build + cnt-bounded dump ----
__device__ __forceinline__ void do_bucket(int task, int tid,
    const int* __restrict__ partCur, const unsigned int* __restrict__ partBuf,
    int* __restrict__ cur_intra, int* __restrict__ cur_inter,
    int* __restrict__ colS_intra, int* __restrict__ colS_inter,
    float* __restrict__ dinv_intra, float* __restrict__ selfnorm,
    float* __restrict__ dinv_inter, float2* __restrict__ pjn0, SMem& sm) {
  if (tid < 64) sm.k.sC[tid] = 0;
  __syncthreads();
  int gp = task >> 1;                      // partition id 0..261
  int half = task & 1;                     // which 32-node half
  int b = gp / P_B;
  int p = gp - b * P_B;
  int cnt = partCur[gp];
  cnt = cnt < CAPP ? cnt : CAPP;
  const unsigned int* buf = partBuf + (size_t)gp * CAPP;
  for (int i = tid; i < cnt; i += 256) {
    unsigned int v = buf[i];
    int off = (v >> 14) & 63;
    if ((off >> 5) != half) continue;
    int o = off & 31;
    int src = v & 0x3FFF;
    int dst = p * 64 + off;
    bool ss = (src < NODE_NUM) && (dst < NODE_NUM);
    bool tt = (src >= NODE_NUM) && (dst >= NODE_NUM);
    if (ss || tt) {
      int pos = atomicAdd(&sm.k.sC[o], 1);
      if (pos < CAP2) sm.k.sIn[o * CAP2 + pos] = src;
    } else {
      int pos = atomicAdd(&sm.k.sC[32 + o], 1);
      if (pos < CAP2) sm.k.sIt[o * CAP2 + pos] = src;
    }
  }
  __syncthreads();
  int dbase = p * 64 + half * 32;
  size_t gbase = ((size_t)b * NN + dbase) * CAP;
  // cnt-bounded dump: only used slots (avg ~31 of 128) -> ~16x fewer writes.
  // Slots >= cnt are never read by the gather (it clamps to cnt).
  for (int j = tid; j < 32 * CAP; j += 256) {
    int off = j >> 7, slot = j & (CAP - 1);
    int ci = sm.k.sC[off];      ci = ci < CAP2 ? ci : CAP2;
    int ct = sm.k.sC[32 + off]; ct = ct < CAP2 ? ct : CAP2;
    if (slot < ci) colS_intra[gbase + j] = (int)sm.k.sIn[off * CAP2 + slot];
    if (slot < ct) colS_inter[gbase + j] = (int)sm.k.sIt[off * CAP2 + slot];
  }
  if (tid < 32) {
    int node = b * NN + dbase + tid;
    int ci = sm.k.sC[tid];      ci = ci < CAP2 ? ci : CAP2;
    int ct = sm.k.sC[32 + tid]; ct = ct < CAP2 ? ct : CAP2;
    cur_intra[node] = ci;
    cur_inter[node] = ct;
    float df = (float)(ci + 1);             // gcn_norm adds a self loop
    float di = rsqrtf(df);
    dinv_intra[node] = di;
    selfnorm[node] = 1.0f / df;
    dinv_inter[node] = (ct > 0) ? (1.0f / (float)ct) : 0.0f;
    pjn0[node].y = di;                      // pair layer-1 pj with its src-norm
  }
  __syncthreads();                          // safe for task-loop LDS reuse
}

// ---- gather: fused edge coefs, bf16 messages, readlane broadcast, 16-deep
//      load groups, PAIRED {pj,ns} random gather, fused NEXT-layer proj ----
template <bool INTRA, bool RELU, bool NEXTPROJ, bool NEXT_INTRA>
__device__ __forceinline__ void gather_node(int wid, int lane,
    const float* __restrict__ h_in, const unsigned int* __restrict__ hm,
    float* __restrict__ h_out, unsigned int* __restrict__ hm_out,
    const int* __restrict__ cnt, const int* __restrict__ colS,
    const float* __restrict__ pi, const float2* __restrict__ pjn,
    const float* __restrict__ normD, const float* __restrict__ selfnorm,
    const float* __restrict__ dinv_intra,
    const float* __restrict__ nWi_s, const float* __restrict__ nWj_s,
    const float* __restrict__ nWi_t, const float* __restrict__ nWj_t,
    float* __restrict__ pi_out, float2* __restrict__ pjn_out) {
  int b = wid / NN;
  int n = wid - b * NN;
  int mt = cnt[wid];
  mt = mt < CAP ? mt : CAP;
  const float* hb = h_in + (size_t)b * NN * CC;
  const unsigned int* hmb = hm + (size_t)b * NN * (CC / 2) + lane;
  const float2* pjnb = pjn + b * NN;
  float p_i = pi[wid];
  float nd = normD[wid];
  const float2 hv = *(const float2*)(hb + (size_t)n * CC + lane * 2);
  float2 acc;
  if (INTRA) {
    float fac = 1.0f + tanhf(p_i + pjnb[n].x) * selfnorm[wid];
    acc.x = hv.x * fac;
    acc.y = hv.y * fac;
  } else {
    acc = hv;  // residual only
  }
  const int* cS = colS + (size_t)wid * CAP;
  for (int off = 0; off < mt; off += 64) {
    int rem = mt - off;
    int m = rem < 64 ? rem : 64;
    int src = 0;
    float c = 0.0f;
    if (lane < m) {
      src = cS[off + lane];
      float2 pn = pjnb[src];                 // one 8B random gather per edge
      float a = tanhf(p_i + pn.x);
      c = a * nd;
      if (INTRA) c *= pn.y;
    }
#pragma unroll
    for (int base = 0; base < 64; base += 16) {
      if (base >= m) break;
      unsigned int u[16];
      float cj[16];
#pragma unroll
      for (int k = 0; k < 16; ++k) {
        int sj = __builtin_amdgcn_readlane(src, base + k);           // SGPR
        cj[k] = __int_as_float(
            __builtin_amdgcn_readlane(__float_as_int(c), base + k)); // SGPR
        u[k] = hmb[sj * (CC / 2)];   // saddr-form load, 16 in flight
      }
#pragma unroll
      for (int k = 0; k < 16; ++k) {
        acc.x = fmaf(bf2f(u[k] & 0xFFFFu), cj[k], acc.x);
        acc.y = fmaf(bf2f(u[k] >> 16), cj[k], acc.y);
      }
    }
  }
  if (RELU) { acc.x = fmaxf(acc.x, 0.0f); acc.y = fmaxf(acc.y, 0.0f); }
  size_t oi = (size_t)wid * (CC / 2) + lane;
  *(float2*)(h_out + 2 * oi) = acc;
  if (NEXTPROJ) {
    hm_out[oi] = (f2bf_u(acc.y) << 16) | f2bf_u(acc.x);
    bool is_s = (n < NODE_NUM);
    const float* wi = is_s ? nWi_s : nWi_t;
    const float* wj = is_s ? nWj_s : nWj_t;
    float2 wiv = *(const float2*)(wi + lane * 2);
    float2 wjv = *(const float2*)(wj + lane * 2);
    float a = acc.x * wiv.x + acc.y * wiv.y;
    float c2 = acc.x * wjv.x + acc.y * wjv.y;
#pragma unroll
    for (int o = 32; o > 0; o >>= 1) {
      a += __shfl_xor(a, o, 64);
      c2 += __shfl_xor(c2, o, 64);
    }
    if (lane == 0) {
      pi_out[wid] = a;
      float2 pn;
      pn.x = c2;
      pn.y = NEXT_INTRA ? dinv_intra[wid] : 0.0f;
      pjn_out[wid] = pn;
    }
  }
}

// ---- single persistent fused kernel: 6 phases, 5 device-scope barriers ----
// launch_bounds(256,4): VGPR<=128 -> 16 waves/CU (m69) -> 4 blocks/CU;
// LDS 31KB -> 5 blocks/CU. Grid = occ*256 is fully co-resident.
__global__ void __launch_bounds__(256, 4)
k_fused(const int* __restrict__ ei, const float* __restrict__ x,
        const float* __restrict__ Wss, const float* __restrict__ Wtt,
        const float* __restrict__ Wst, const float* __restrict__ Wts,
        float* __restrict__ out,
        int* __restrict__ partCur, unsigned int* __restrict__ partBuf,
        int* __restrict__ gbar,
        unsigned int* __restrict__ xb, float* __restrict__ h0,
        unsigned int* __restrict__ mb0, float* __restrict__ h1,
        unsigned int* __restrict__ mb1,
        float* __restrict__ pi0, float* __restrict__ pi1,
        float2* __restrict__ pjn0, float2* __restrict__ pjn1,
        float* __restrict__ dinv_intra, float* __restrict__ selfnorm,
        float* __restrict__ dinv_inter,
        int* __restrict__ cur_intra, int* __restrict__ cur_inter,
        int* __restrict__ colS_intra, int* __restrict__ colS_inter) {
  __shared__ SMem sm;
  int tid = threadIdx.x;
  int lane = tid & 63;
  int nb = (int)gridDim.x;
  const float* wss0 = Wss, *wtt0 = Wtt, *wst0 = Wst, *wts0 = Wts;
  const float* wss1 = Wss + 256, *wtt1 = Wtt + 256;
  const float* wst1 = Wst + 256, *wts1 = Wts + 256;

  // phase 0: edge partition (blocks < FILLB) || node init (the rest)
  if (blockIdx.x < FILLB) {
    do_fill(blockIdx.x, tid, ei, partCur, partBuf, sm);
  } else {
    int gw0 = (((int)blockIdx.x - FILLB) * 256 + tid) >> 6;
    int nw0 = ((nb - FILLB) * 256) >> 6;
    for (int wid = gw0; wid < NTASK; wid += nw0)
      node_init(wid, lane, x, xb, wss0, wss0 + 128, wtt0, wtt0 + 128, pi0, pjn0);
  }
  grid_barrier(gbar, nb);

  // phase 1: bucket build (524 half-partition tasks)
  for (int t = blockIdx.x; t < BB * P_B * 2; t += nb)
    do_bucket(t, tid, partCur, partBuf, cur_intra, cur_inter,
              colS_intra, colS_inter, dinv_intra, selfnorm, dinv_inter, pjn0, sm);
  grid_barrier(gbar, 2 * nb);

  int gw = ((int)blockIdx.x * 256 + tid) >> 6;
  int nw = (nb * 256) >> 6;

  // layer 1 (intra, relu): (x,xb) -> (h0,mb0); fused proj for layer 2 (inter)
  for (int wid = gw; wid < NTASK; wid += nw)
    gather_node<true, true, true, false>(wid, lane, x, xb, h0, mb0,
        cur_intra, colS_intra, pi0, pjn0, dinv_intra, selfnorm, dinv_intra,
        wts0, wst0 + 128, wst0, wts0 + 128, pi1, pjn1);
  grid_barrier(gbar, 3 * nb);

  // layer 2 (inter, relu): (h0,mb0) -> (h1,mb1); fused proj for layer 3 (intra)
  for (int wid = gw; wid < NTASK; wid += nw)
    gather_node<false, true, true, true>(wid, lane, h0, mb0, h1, mb1,
        cur_inter, colS_inter, pi1, pjn1, dinv_inter, selfnorm, dinv_intra,
        wss1, wss1 + 128, wtt1, wtt1 + 128, pi0, pjn0);
  grid_barrier(gbar, 4 * nb);

  // layer 3 (intra, relu): (h1,mb1) -> (h0,mb0); fused proj for layer 4 (inter)
  for (int wid = gw; wid < NTASK; wid += nw)
    gather_node<true, true, true, false>(wid, lane, h1, mb1, h0, mb0,
        cur_intra, colS_intra, pi0, pjn0, dinv_intra, selfnorm, dinv_intra,
        wts1, wst1 + 128, wst1, wts1 + 128, pi1, pjn1);
  grid_barrier(gbar, 5 * nb);

  // layer 4 (inter, no relu): (h0,mb0) -> out
  for (int wid = gw; wid < NTASK; wid += nw)
    gather_node<false, false, false, false>(wid, lane, h0, mb0, out,
        (unsigned int*)nullptr, cur_inter, colS_inter, pi1, pjn1, dinv_inter,
        selfnorm, dinv_intra, (const float*)nullptr, (const float*)nullptr,
        (const float*)nullptr, (const float*)nullptr,
        (float*)nullptr, (float2*)nullptr);
}

extern "C" void kernel_launch(void* const* d_in, const int* in_sizes, int n_in,
                              void* d_out, int out_size, void* d_ws, size_t ws_size,
                              hipStream_t stream) {
  const float* x = (const float*)d_in[0];      // fp32 features [B,N,C]
  const int* ei = (const int*)d_in[1];         // int32 [B,2,E]
  const float* Wss = (const float*)d_in[2];    // fp32 [2, 2C]
  const float* Wtt = (const float*)d_in[3];
  const float* Wst = (const float*)d_in[4];
  const float* Wts = (const float*)d_in[5];
  float* out = (float*)d_out;                  // fp32 output [B,N,C]

  char* p = (char*)d_ws;
  auto alloc = [&](size_t bytes) {
    void* r = (void*)p;
    p += ((bytes + 255) & ~(size_t)255);
    return r;
  };
  float* h0 = (float*)alloc((size_t)BB * NN * CC * 4);
  float* h1 = (float*)alloc((size_t)BB * NN * CC * 4);
  unsigned int* xb = (unsigned int*)alloc((size_t)BB * NN * CC * 2);  // bf16 mirrors
  unsigned int* mb0 = (unsigned int*)alloc((size_t)BB * NN * CC * 2);
  unsigned int* mb1 = (unsigned int*)alloc((size_t)BB * NN * CC * 2);
  float* pi0 = (float*)alloc(BB * NN * 4);
  float* pi1 = (float*)alloc(BB * NN * 4);
  float2* pjn0 = (float2*)alloc(BB * NN * 8);   // paired {pj, src-norm}
  float2* pjn1 = (float2*)alloc(BB * NN * 8);
  float* dinv_intra = (float*)alloc(BB * NN * 4);
  float* selfnorm = (float*)alloc(BB * NN * 4);
  float* dinv_inter = (float*)alloc(BB * NN * 4);
  int* cur_intra = (int*)alloc(BB * NN * 4);
  int* cur_inter = (int*)alloc(BB * NN * 4);
  int* colS_intra = (int*)alloc((size_t)BB * NN * CAP * 4);  // 8.6 MB buckets
  int* colS_inter = (int*)alloc((size_t)BB * NN * CAP * 4);
  int* partCur = (int*)alloc(BB * P_B * 4);                  // 262 cursors
  int* gbar = (int*)alloc(256);                              // grid barrier counter
  unsigned int* partBuf = (unsigned int*)alloc((size_t)BB * P_B * CAPP * 4);

  // zero cursors + barrier counter in one in-graph memset (contiguous allocs)
  hipMemsetAsync(partCur, 0, (size_t)((char*)gbar - (char*)partCur) + 256, stream);

  // Grid sizing: must be fully co-resident for the device-scope barrier.
  // launch_bounds(256,4) + 31KB LDS -> occupancy API should report 4/CU.
  int occ = 0;
  if (hipOccupancyMaxActiveBlocksPerMultiprocessor(&occ, k_fused, 256, 0) != hipSuccess ||
      occ <= 0)
    occ = 4;
  if (occ > 8) occ = 8;
  int grid = occ * 256;                        // 256 CUs on MI355X
  if (grid < 2 * FILLB) grid = 2 * FILLB;      // ensure node-init blocks exist

  k_fused<<<grid, 256, 0, stream>>>(
      ei, x, Wss, Wtt, Wst, Wts, out,
      partCur, partBuf, gbar,
      xb, h0, mb0, h1, mb1,
      pi0, pi1, pjn0, pjn1,
      dinv_intra, selfnorm, dinv_inter,
      cur_intra, cur_inter, colS_intra, colS_inter);
}

// Round 2
// 144.499 us; speedup vs baseline: 6.3528x; 6.3528x over previous
//
#include <hip/hip_runtime.h>
#include <stdint.h>

#define NODE_NUM 8192
#define NN 8384        // total nodes per graph (8384 = 131*64)
#define CC 128         // channels
#define BB 2           // batch
#define EE 262144      // edges per graph (2^18)
#define CAP 128        // global bucket stride per (node,kind)
#define CAP2 120       // LDS bucket capacity (max degree ~60, Poisson lambda~31)
#define P_B 131        // partitions per batch, 64 nodes each (131*64 = 8384)
#define CAPP 4096      // partition buffer capacity (expected ~2000 +- 45)
#define FILLB 256      // phase-1 fill blocks (256 * 2048 = 2^19 edges)

__device__ __forceinline__ unsigned int f2bf_u(float f) {
  unsigned int u = __float_as_uint(f);
  return (u + 0x7FFFu + ((u >> 16) & 1u)) >> 16;
}
__device__ __forceinline__ float bf2f(unsigned int u) {
  return __uint_as_float(u << 16);
}

// ---- phase 1: LDS-segmented edge partitioning (+ fused init for x) ----
// Blocks [0,FILLB): segment 2048 contiguous edges by dst>>6 in LDS, claim
// global ranges with ONE atomic per partition, flush packed (p|off|src).
// Blocks [FILLB,+NODE_BLOCKS): bf16-pack x + layer-1 projections (1 wave/node).
// pjn0.x = layer-1 pj; .y (dinv_intra) is filled by k_bucket afterwards.
// NOTE (R1 lesson): do NOT fuse these phases with device-scope barriers —
// per-thread __threadfence storms whole-L2 wb/inv ops and 6x-regressed.
__global__ void k_part_init(const int* __restrict__ ei,
                            int* __restrict__ partCur, unsigned int* __restrict__ partBuf,
                            const float* __restrict__ x, unsigned int* __restrict__ xb,
                            const float* __restrict__ Wi_s, const float* __restrict__ Wj_s,
                            const float* __restrict__ Wi_t, const float* __restrict__ Wj_t,
                            float* __restrict__ pi, float2* __restrict__ pjn) {
  if (blockIdx.x < FILLB) {
    __shared__ unsigned int sEdge[2048];
    __shared__ int sCnt[P_B];
    __shared__ int sOff[P_B + 1];
    __shared__ int sBase[P_B];
    int tid = threadIdx.x;
    int b = blockIdx.x >> 7;                 // 128 blocks per batch
    int e0 = (blockIdx.x & 127) * 2048;
    const int* eb = ei + b * 2 * EE;
    for (int i = tid; i < P_B; i += 256) sCnt[i] = 0;
    __syncthreads();
    const int4* s4 = (const int4*)(eb + e0 + tid * 8);
    const int4* d4 = (const int4*)(eb + EE + e0 + tid * 8);
    int4 sa = s4[0], sb_ = s4[1], da = d4[0], db_ = d4[1];
    int srcs[8] = {sa.x, sa.y, sa.z, sa.w, sb_.x, sb_.y, sb_.z, sb_.w};
    int dsts[8] = {da.x, da.y, da.z, da.w, db_.x, db_.y, db_.z, db_.w};
    unsigned int cache[8];
#pragma unroll
    for (int k = 0; k < 8; ++k) {
      int src = srcs[k], dst = dsts[k];
      if ((unsigned)src >= NN || (unsigned)dst >= NN) { cache[k] = 0xFFFFFFFFu; continue; }
      int p = dst >> 6;
      cache[k] = ((unsigned)p << 20) | ((unsigned)(dst & 63) << 14) | (unsigned)src;
      atomicAdd(&sCnt[p], 1);
    }
    __syncthreads();
    if (tid == 0) {                          // serial prefix over 131 entries
      int acc = 0;
      for (int i = 0; i < P_B; ++i) { sOff[i] = acc; acc += sCnt[i]; }
      sOff[P_B] = acc;
    }
    __syncthreads();
    if (tid < P_B) sBase[tid] = atomicAdd(&partCur[b * P_B + tid], sCnt[tid]);
    __syncthreads();
    if (tid < P_B) sCnt[tid] = 0;            // reuse as placement cursor
    __syncthreads();
#pragma unroll
    for (int k = 0; k < 8; ++k) {
      unsigned int v = cache[k];
      if (v == 0xFFFFFFFFu) continue;
      int p = v >> 20;
      int pos = atomicAdd(&sCnt[p], 1);
      sEdge[sOff[p] + pos] = v;
    }
    __syncthreads();
    int total = sOff[P_B];
    for (int i = tid; i < total; i += 256) {
      unsigned int v = sEdge[i];
      int p = v >> 20;
      int idx = (i - sOff[p]) + sBase[p];
      if (idx < CAPP)
        partBuf[(size_t)(b * P_B + p) * CAPP + idx] = v & 0xFFFFFu;  // off|src
    }
  } else {
    int wid = ((blockIdx.x - FILLB) * blockDim.x + threadIdx.x) >> 6;  // b*NN+n
    int lane = threadIdx.x & 63;
    int n = wid % NN;
    bool is_s = (n < NODE_NUM);
    const float* wi = is_s ? Wi_s : Wi_t;
    const float* wj = is_s ? Wj_s : Wj_t;
    size_t oi = (size_t)wid * (CC / 2) + lane;
    float2 hv = ((const float2*)x)[oi];
    xb[oi] = (f2bf_u(hv.y) << 16) | f2bf_u(hv.x);
    float2 wiv = *(const float2*)(wi + lane * 2);
    float2 wjv = *(const float2*)(wj + lane * 2);
    float a = hv.x * wiv.x + hv.y * wiv.y;
    float c = hv.x * wjv.x + hv.y * wjv.y;
#pragma unroll
    for (int o = 32; o > 0; o >>= 1) {
      a += __shfl_xor(a, o, 64);
      c += __shfl_xor(c, o, 64);
    }
    if (lane == 0) { pi[wid] = a; pjn[wid].x = c; }
  }
}

// ---- phase 2: per-HALF-partition (32 nodes) LDS bucket build + cnt-bounded
// dump + fused norms. 524 blocks (2 per partition), 31KB LDS -> ~2 blocks/CU
// (was 262 blocks @62KB = 1/CU). Dump writes only cnt used slots (~31/128):
// slots >= cnt are never read (gather clamps to cnt), so poison is safe.
// Also fills pjn0.y = dinv_intra (used by layer-1 intra coef).
__global__ void k_bucket(const int* __restrict__ partCur, const unsigned int* __restrict__ partBuf,
                         int* __restrict__ cur_intra, int* __restrict__ cur_inter,
                         int* __restrict__ colS_intra, int* __restrict__ colS_inter,
                         float* __restrict__ dinv_intra, float* __restrict__ selfnorm,
                         float* __restrict__ dinv_inter, float2* __restrict__ pjn0) {
  __shared__ unsigned int sIn[32 * CAP2];
  __shared__ unsigned int sIt[32 * CAP2];
  __shared__ int sC[64];                     // [0..31] intra, [32..63] inter
  int tid = threadIdx.x;
  int task = blockIdx.x;                     // 0..523
  int gp = task >> 1;                        // partition id 0..261
  int half = task & 1;                       // which 32-node half
  int b = gp / P_B;
  int p = gp - b * P_B;
  if (tid < 64) sC[tid] = 0;
  __syncthreads();
  int cnt = partCur[gp];
  cnt = cnt < CAPP ? cnt : CAPP;
  const unsigned int* buf = partBuf + (size_t)gp * CAPP;
  for (int i = tid; i < cnt; i += 256) {
    unsigned int v = buf[i];
    int off = (v >> 14) & 63;
    if ((off >> 5) != half) continue;
    int o = off & 31;
    int src = v & 0x3FFF;
    int dst = p * 64 + off;
    bool ss = (src < NODE_NUM) && (dst < NODE_NUM);
    bool tt = (src >= NODE_NUM) && (dst >= NODE_NUM);
    if (ss || tt) {
      int pos = atomicAdd(&sC[o], 1);
      if (pos < CAP2) sIn[o * CAP2 + pos] = src;
    } else {
      int pos = atomicAdd(&sC[32 + o], 1);
      if (pos < CAP2) sIt[o * CAP2 + pos] = src;
    }
  }
  __syncthreads();
  int dbase = p * 64 + half * 32;
  size_t gbase = ((size_t)b * NN + dbase) * CAP;
  for (int j = tid; j < 32 * CAP; j += 256) {
    int off = j >> 7, slot = j & (CAP - 1);
    int ci = sC[off];      ci = ci < CAP2 ? ci : CAP2;
    int ct = sC[32 + off]; ct = ct < CAP2 ? ct : CAP2;
    if (slot < ci) colS_intra[gbase + j] = (int)sIn[off * CAP2 + slot];
    if (slot < ct) colS_inter[gbase + j] = (int)sIt[off * CAP2 + slot];
  }
  if (tid < 32) {
    int node = b * NN + dbase + tid;
    int ci = sC[tid];       ci = ci < CAP2 ? ci : CAP2;
    int ct = sC[32 + tid];  ct = ct < CAP2 ? ct : CAP2;
    cur_intra[node] = ci;
    cur_inter[node] = ct;
    float df = (float)(ci + 1);             // gcn_norm adds a self loop
    float di = rsqrtf(df);
    dinv_intra[node] = di;
    selfnorm[node] = 1.0f / df;
    dinv_inter[node] = (ct > 0) ? (1.0f / (float)ct) : 0.0f;
    pjn0[node].y = di;                      // pair layer-1 pj with its src-norm
  }
}

// ---- gather: fused edge coefs, bf16 messages, readlane broadcast, 16-deep
//      load groups, PAIRED {pj,ns} random gather (1 load/edge instead of 2),
//      fused NEXT-layer projection in the epilogue ----
template <bool INTRA, bool RELU, bool NEXTPROJ, bool NEXT_INTRA>
__global__ void __launch_bounds__(256, 6)
k_gather(const float* __restrict__ h_in, const unsigned int* __restrict__ hm,
         float* __restrict__ h_out, unsigned int* __restrict__ hm_out,
         const int* __restrict__ cnt, const int* __restrict__ colS,
         const float* __restrict__ pi, const float2* __restrict__ pjn,
         const float* __restrict__ normD, const float* __restrict__ selfnorm,
         const float* __restrict__ dinv_intra,
         const float* __restrict__ nWi_s, const float* __restrict__ nWj_s,
         const float* __restrict__ nWi_t, const float* __restrict__ nWj_t,
         float* __restrict__ pi_out, float2* __restrict__ pjn_out) {
  int wid = (blockIdx.x * blockDim.x + threadIdx.x) >> 6;
  int lane = threadIdx.x & 63;
  int b = wid / NN;
  int n = wid - b * NN;
  int mt = cnt[wid];
  mt = mt < CAP ? mt : CAP;
  const float* hb = h_in + (size_t)b * NN * CC;
  const unsigned int* hmb = hm + (size_t)b * NN * (CC / 2) + lane;
  const float2* pjnb = pjn + b * NN;
  float p_i = pi[wid];
  float nd = normD[wid];
  const float2 hv = *(const float2*)(hb + (size_t)n * CC + lane * 2);
  float2 acc;
  if (INTRA) {
    // residual + self-loop message: h * (1 + tanh(pi+pj)/deg)  (fp32 path)
    float fac = 1.0f + tanhf(p_i + pjnb[n].x) * selfnorm[wid];
    acc.x = hv.x * fac;
    acc.y = hv.y * fac;
  } else {
    acc = hv;  // residual only
  }
  const int* cS = colS + (size_t)wid * CAP;
  for (int off = 0; off < mt; off += 64) {
    int rem = mt - off;
    int m = rem < 64 ? rem : 64;
    int src = 0;
    float c = 0.0f;
    if (lane < m) {
      src = cS[off + lane];
      float2 pn = pjnb[src];                 // one 8B random gather per edge
      float a = tanhf(p_i + pn.x);
      c = a * nd;
      if (INTRA) c *= pn.y;
    }
#pragma unroll
    for (int base = 0; base < 64; base += 16) {
      if (base >= m) break;
      unsigned int u[16];
      float cj[16];
#pragma unroll
      for (int k = 0; k < 16; ++k) {
        int sj = __builtin_amdgcn_readlane(src, base + k);          // SGPR
        cj[k] = __int_as_float(
            __builtin_amdgcn_readlane(__float_as_int(c), base + k)); // SGPR
        u[k] = hmb[sj * (CC / 2)];   // saddr-form load, 16 in flight
      }
#pragma unroll
      for (int k = 0; k < 16; ++k) {
        acc.x = fmaf(bf2f(u[k] & 0xFFFFu), cj[k], acc.x);
        acc.y = fmaf(bf2f(u[k] >> 16), cj[k], acc.y);
      }
    }
  }
  if (RELU) { acc.x = fmaxf(acc.x, 0.0f); acc.y = fmaxf(acc.y, 0.0f); }
  size_t oi = (size_t)wid * (CC / 2) + lane;
  *(float2*)(h_out + 2 * oi) = acc;
  if (NEXTPROJ) {
    hm_out[oi] = (f2bf_u(acc.y) << 16) | f2bf_u(acc.x);
    bool is_s = (n < NODE_NUM);
    const float* wi = is_s ? nWi_s : nWi_t;
    const float* wj = is_s ? nWj_s : nWj_t;
    float2 wiv = *(const float2*)(wi + lane * 2);
    float2 wjv = *(const float2*)(wj + lane * 2);
    float a = acc.x * wiv.x + acc.y * wiv.y;
    float c2 = acc.x * wjv.x + acc.y * wjv.y;
#pragma unroll
    for (int o = 32; o > 0; o >>= 1) {
      a += __shfl_xor(a, o, 64);
      c2 += __shfl_xor(c2, o, 64);
    }
    if (lane == 0) {
      pi_out[wid] = a;
      float2 pn;
      pn.x = c2;
      pn.y = NEXT_INTRA ? dinv_intra[wid] : 0.0f;
      pjn_out[wid] = pn;
    }
  }
}

extern "C" void kernel_launch(void* const* d_in, const int* in_sizes, int n_in,
                              void* d_out, int out_size, void* d_ws, size_t ws_size,
                              hipStream_t stream) {
  const float* x = (const float*)d_in[0];      // fp32 features [B,N,C]
  const int* ei = (const int*)d_in[1];         // int32 [B,2,E]
  const float* Wss = (const float*)d_in[2];    // fp32 [2, 2C]
  const float* Wtt = (const float*)d_in[3];
  const float* Wst = (const float*)d_in[4];
  const float* Wts = (const float*)d_in[5];
  float* out = (float*)d_out;                  // fp32 output [B,N,C]

  char* p = (char*)d_ws;
  auto alloc = [&](size_t bytes) {
    void* r = (void*)p;
    p += ((bytes + 255) & ~(size_t)255);
    return r;
  };
  float* h0 = (float*)alloc((size_t)BB * NN * CC * 4);
  float* h1 = (float*)alloc((size_t)BB * NN * CC * 4);
  unsigned int* xb = (unsigned int*)alloc((size_t)BB * NN * CC * 2);  // bf16 mirrors
  unsigned int* mb0 = (unsigned int*)alloc((size_t)BB * NN * CC * 2);
  unsigned int* mb1 = (unsigned int*)alloc((size_t)BB * NN * CC * 2);
  float* pi0 = (float*)alloc(BB * NN * 4);
  float* pi1 = (float*)alloc(BB * NN * 4);
  float2* pjn0 = (float2*)alloc(BB * NN * 8);   // paired {pj, src-norm}
  float2* pjn1 = (float2*)alloc(BB * NN * 8);
  float* dinv_intra = (float*)alloc(BB * NN * 4);
  float* selfnorm = (float*)alloc(BB * NN * 4);
  float* dinv_inter = (float*)alloc(BB * NN * 4);
  int* cur_intra = (int*)alloc(BB * NN * 4);
  int* cur_inter = (int*)alloc(BB * NN * 4);
  int* colS_intra = (int*)alloc((size_t)BB * NN * CAP * 4);  // 8.6 MB buckets
  int* colS_inter = (int*)alloc((size_t)BB * NN * CAP * 4);
  int* partCur = (int*)alloc(BB * P_B * 4);                  // 262 cursors
  unsigned int* partBuf = (unsigned int*)alloc((size_t)BB * P_B * CAPP * 4);  // 4.3 MB
  // total ws use: ~50 MB

  hipMemsetAsync(partCur, 0, BB * P_B * 4, stream);

  const int NODE_BLOCKS = (BB * NN * 64) / 256;  // 1 wave per node, 4 waves/block
  const float* wss0 = Wss, *wtt0 = Wtt, *wst0 = Wst, *wts0 = Wts;
  const float* wss1 = Wss + 256, *wtt1 = Wtt + 256, *wst1 = Wst + 256, *wts1 = Wts + 256;

  // phase 1 (edge partition) + init (pack x, layer-1 intra proj -> pi0/pjn0.x)
  k_part_init<<<FILLB + NODE_BLOCKS, 256, 0, stream>>>(
      ei, partCur, partBuf, x, xb, wss0, wss0 + 128, wtt0, wtt0 + 128, pi0, pjn0);
  // phase 2 (LDS bucket build, cnt-bounded dump, fused norms, pjn0.y)
  k_bucket<<<BB * P_B * 2, 256, 0, stream>>>(partCur, partBuf, cur_intra, cur_inter,
                                             colS_intra, colS_inter,
                                             dinv_intra, selfnorm, dinv_inter, pjn0);

  // layer 1 (intra, relu): (x,xb) -> (h0,mb0); fused proj for layer 2 (inter)
  // inter proj: s-node pi=W_ts[:C], pj=W_st[C:]; t-node pi=W_st[:C], pj=W_ts[C:]
  k_gather<true, true, true, false><<<NODE_BLOCKS, 256, 0, stream>>>(
      x, xb, h0, mb0, cur_intra, colS_intra, pi0, pjn0, dinv_intra, selfnorm, dinv_intra,
      wts0, wst0 + 128, wst0, wts0 + 128, pi1, pjn1);

  // layer 2 (inter, relu): (h0,mb0) -> (h1,mb1); fused proj for layer 3 (intra)
  k_gather<false, true, true, true><<<NODE_BLOCKS, 256, 0, stream>>>(
      h0, mb0, h1, mb1, cur_inter, colS_inter, pi1, pjn1, dinv_inter, selfnorm, dinv_intra,
      wss1, wss1 + 128, wtt1, wtt1 + 128, pi0, pjn0);

  // layer 3 (intra, relu): (h1,mb1) -> (h0,mb0); fused proj for layer 4 (inter)
  k_gather<true, true, true, false><<<NODE_BLOCKS, 256, 0, stream>>>(
      h1, mb1, h0, mb0, cur_intra, colS_intra, pi0, pjn0, dinv_intra, selfnorm, dinv_intra,
      wts1, wst1 + 128, wst1, wts1 + 128, pi1, pjn1);

  // layer 4 (inter, no relu): (h0,mb0) -> d_out; no next proj
  k_gather<false, false, false, false><<<NODE_BLOCKS, 256, 0, stream>>>(
      h0, mb0, out, nullptr, cur_inter, colS_inter, pi1, pjn1, dinv_inter, selfnorm,
      dinv_intra, nullptr, nullptr, nullptr, nullptr, nullptr, nullptr);
}

// Round 3
// 143.876 us; speedup vs baseline: 6.3803x; 1.0043x over previous
//
#include <hip/hip_runtime.h>
#include <stdint.h>

#define NODE_NUM 8192
#define NN 8384        // total nodes per graph (8384 = 131*64)
#define CC 128         // channels
#define BB 2           // batch
#define EE 262144      // edges per graph (2^18)
#define CAP 128        // global bucket stride per (node,kind)
#define CAP2 120       // LDS bucket capacity (max degree ~60, Poisson lambda~31)
#define P_B 131        // partitions per batch, 64 nodes each (131*64 = 8384)
#define CAPP 4096      // partition buffer capacity (expected ~2000 +- 45)
#define FILLB 256      // phase-1 fill blocks (256 * 2048 = 2^19 edges)

// ---- batch-affine XCD swizzle -------------------------------------------
// blockIdx -> XCD is round-robin %8 on MI355X (measured, learn_hip m09).
// batch = xcd>>2: each batch's random-gather working set (bf16 mirror 4.3MB
// + pjn) stays inside 4 XCDs' L2s (4.3MB vs 8.6MB combined -> L2-resident).
// quartile = xcd&3 aligned by node range in EVERY kernel so producers and
// consumers of xb/mb/h/colS/partBuf meet in the same XCD's L2.
// Perf heuristic only: if the %8 mapping changes, behavior = old random.

__device__ __forceinline__ unsigned int f2bf_u(float f) {
  unsigned int u = __float_as_uint(f);
  return (u + 0x7FFFu + ((u >> 16) & 1u)) >> 16;
}
__device__ __forceinline__ float bf2f(unsigned int u) {
  return __uint_as_float(u << 16);
}

// ---- phase 1: LDS-segmented edge partitioning (+ fused init for x) ----
// Blocks [0,FILLB): segment 2048 contiguous edges by dst>>6 in LDS, claim
// global ranges with ONE atomic per partition, flush packed (p|off|src).
// Blocks [FILLB,+NODE_BLOCKS): bf16-pack x + layer-1 projections (1 wave/node).
// NOTE (R1 lesson): do NOT fuse phases with device-scope barriers —
// per-thread __threadfence storms whole-L2 wb/inv ops and 6x-regressed.
__global__ void k_part_init(const int* __restrict__ ei,
                            int* __restrict__ partCur, unsigned int* __restrict__ partBuf,
                            const float* __restrict__ x, unsigned int* __restrict__ xb,
                            const float* __restrict__ Wi_s, const float* __restrict__ Wj_s,
                            const float* __restrict__ Wi_t, const float* __restrict__ Wj_t,
                            float* __restrict__ pi, float2* __restrict__ pjn) {
  if (blockIdx.x < FILLB) {
    __shared__ unsigned int sEdge[2048];
    __shared__ int sCnt[P_B];
    __shared__ int sOff[P_B + 1];
    __shared__ int sBase[P_B];
    int tid = threadIdx.x;
    // swizzle: xcd = bi&7; b = xcd>>2; chunk = (xcd&3)*32 + bi>>3  (128/batch)
    int xcd = blockIdx.x & 7;
    int b = xcd >> 2;
    int e0 = ((xcd & 3) * 32 + (blockIdx.x >> 3)) * 2048;
    const int* eb = ei + b * 2 * EE;
    for (int i = tid; i < P_B; i += 256) sCnt[i] = 0;
    __syncthreads();
    const int4* s4 = (const int4*)(eb + e0 + tid * 8);
    const int4* d4 = (const int4*)(eb + EE + e0 + tid * 8);
    int4 sa = s4[0], sb_ = s4[1], da = d4[0], db_ = d4[1];
    int srcs[8] = {sa.x, sa.y, sa.z, sa.w, sb_.x, sb_.y, sb_.z, sb_.w};
    int dsts[8] = {da.x, da.y, da.z, da.w, db_.x, db_.y, db_.z, db_.w};
    unsigned int cache[8];
#pragma unroll
    for (int k = 0; k < 8; ++k) {
      int src = srcs[k], dst = dsts[k];
      if ((unsigned)src >= NN || (unsigned)dst >= NN) { cache[k] = 0xFFFFFFFFu; continue; }
      int p = dst >> 6;
      cache[k] = ((unsigned)p << 20) | ((unsigned)(dst & 63) << 14) | (unsigned)src;
      atomicAdd(&sCnt[p], 1);
    }
    __syncthreads();
    if (tid == 0) {                          // serial prefix over 131 entries
      int acc = 0;
      for (int i = 0; i < P_B; ++i) { sOff[i] = acc; acc += sCnt[i]; }
      sOff[P_B] = acc;
    }
    __syncthreads();
    if (tid < P_B) sBase[tid] = atomicAdd(&partCur[b * P_B + tid], sCnt[tid]);
    __syncthreads();
    if (tid < P_B) sCnt[tid] = 0;            // reuse as placement cursor
    __syncthreads();
#pragma unroll
    for (int k = 0; k < 8; ++k) {
      unsigned int v = cache[k];
      if (v == 0xFFFFFFFFu) continue;
      int p = v >> 20;
      int pos = atomicAdd(&sCnt[p], 1);
      sEdge[sOff[p] + pos] = v;
    }
    __syncthreads();
    int total = sOff[P_B];
    for (int i = tid; i < total; i += 256) {
      unsigned int v = sEdge[i];
      int p = v >> 20;
      int idx = (i - sOff[p]) + sBase[p];
      if (idx < CAPP)
        partBuf[(size_t)(b * P_B + p) * CAPP + idx] = v & 0xFFFFFu;  // off|src
    }
  } else {
    // swizzle: j = bi-FILLB (FILLB%8==0 so j&7 == bi&7 keeps XCD identity)
    int j = blockIdx.x - FILLB;
    int xcd = j & 7;
    int b = xcd >> 2;
    int u = (xcd & 3) * 524 + (j >> 3);      // node-block within batch [0,2096)
    int wid = b * NN + u * 4 + (threadIdx.x >> 6);
    int lane = threadIdx.x & 63;
    int n = wid % NN;
    bool is_s = (n < NODE_NUM);
    const float* wi = is_s ? Wi_s : Wi_t;
    const float* wj = is_s ? Wj_s : Wj_t;
    size_t oi = (size_t)wid * (CC / 2) + lane;
    float2 hv = ((const float2*)x)[oi];
    xb[oi] = (f2bf_u(hv.y) << 16) | f2bf_u(hv.x);
    float2 wiv = *(const float2*)(wi + lane * 2);
    float2 wjv = *(const float2*)(wj + lane * 2);
    float a = hv.x * wiv.x + hv.y * wiv.y;
    float c = hv.x * wjv.x + hv.y * wjv.y;
#pragma unroll
    for (int o = 32; o > 0; o >>= 1) {
      a += __shfl_xor(a, o, 64);
      c += __shfl_xor(c, o, 64);
    }
    if (lane == 0) { pi[wid] = a; pjn[wid].x = c; }
  }
}

// ---- phase 2: per-HALF-partition (32 nodes) LDS bucket build + cnt-bounded
// dump + fused norms. 528 blocks (idx>=262 idle), 31KB LDS -> ~2 blocks/CU.
// Dump writes only cnt used slots; slots >= cnt never read (gather clamps).
__global__ void k_bucket(const int* __restrict__ partCur, const unsigned int* __restrict__ partBuf,
                         int* __restrict__ cur_intra, int* __restrict__ cur_inter,
                         int* __restrict__ colS_intra, int* __restrict__ colS_inter,
                         float* __restrict__ dinv_intra, float* __restrict__ selfnorm,
                         float* __restrict__ dinv_inter, float2* __restrict__ pjn0) {
  __shared__ unsigned int sIn[32 * CAP2];
  __shared__ unsigned int sIt[32 * CAP2];
  __shared__ int sC[64];                     // [0..31] intra, [32..63] inter
  int tid = threadIdx.x;
  // swizzle: b = xcd>>2; idx = (xcd&3)*66 + bi>>3 in [0,264); guard < 262
  int xcd = blockIdx.x & 7;
  int b = xcd >> 2;
  int idx = (xcd & 3) * 66 + (blockIdx.x >> 3);
  if (idx >= 2 * P_B) return;                // block-uniform early out
  int p = idx >> 1;                          // partition within batch
  int half = idx & 1;                        // which 32-node half
  int gp = b * P_B + p;
  if (tid < 64) sC[tid] = 0;
  __syncthreads();
  int cnt = partCur[gp];
  cnt = cnt < CAPP ? cnt : CAPP;
  const unsigned int* buf = partBuf + (size_t)gp * CAPP;
  for (int i = tid; i < cnt; i += 256) {
    unsigned int v = buf[i];
    int off = (v >> 14) & 63;
    if ((off >> 5) != half) continue;
    int o = off & 31;
    int src = v & 0x3FFF;
    int dst = p * 64 + off;
    bool ss = (src < NODE_NUM) && (dst < NODE_NUM);
    bool tt = (src >= NODE_NUM) && (dst >= NODE_NUM);
    if (ss || tt) {
      int pos = atomicAdd(&sC[o], 1);
      if (pos < CAP2) sIn[o * CAP2 + pos] = src;
    } else {
      int pos = atomicAdd(&sC[32 + o], 1);
      if (pos < CAP2) sIt[o * CAP2 + pos] = src;
    }
  }
  __syncthreads();
  int dbase = p * 64 + half * 32;
  size_t gbase = ((size_t)b * NN + dbase) * CAP;
  for (int j = tid; j < 32 * CAP; j += 256) {
    int off = j >> 7, slot = j & (CAP - 1);
    int ci = sC[off];      ci = ci < CAP2 ? ci : CAP2;
    int ct = sC[32 + off]; ct = ct < CAP2 ? ct : CAP2;
    if (slot < ci) colS_intra[gbase + j] = (int)sIn[off * CAP2 + slot];
    if (slot < ct) colS_inter[gbase + j] = (int)sIt[off * CAP2 + slot];
  }
  if (tid < 32) {
    int node = b * NN + dbase + tid;
    int ci = sC[tid];       ci = ci < CAP2 ? ci : CAP2;
    int ct = sC[32 + tid];  ct = ct < CAP2 ? ct : CAP2;
    cur_intra[node] = ci;
    cur_inter[node] = ct;
    float df = (float)(ci + 1);             // gcn_norm adds a self loop
    float di = rsqrtf(df);
    dinv_intra[node] = di;
    selfnorm[node] = 1.0f / df;
    dinv_inter[node] = (ct > 0) ? (1.0f / (float)ct) : 0.0f;
    pjn0[node].y = di;                      // pair layer-1 pj with its src-norm
  }
}

// ---- gather: fused edge coefs, bf16 messages, readlane broadcast, 16-deep
//      load groups, PAIRED {pj,ns} random gather (1 load/edge instead of 2),
//      fused NEXT-layer projection in the epilogue ----
template <bool INTRA, bool RELU, bool NEXTPROJ, bool NEXT_INTRA>
__global__ void __launch_bounds__(256, 6)
k_gather(const float* __restrict__ h_in, const unsigned int* __restrict__ hm,
         float* __restrict__ h_out, unsigned int* __restrict__ hm_out,
         const int* __restrict__ cnt, const int* __restrict__ colS,
         const float* __restrict__ pi, const float2* __restrict__ pjn,
         const float* __restrict__ normD, const float* __restrict__ selfnorm,
         const float* __restrict__ dinv_intra,
         const float* __restrict__ nWi_s, const float* __restrict__ nWj_s,
         const float* __restrict__ nWi_t, const float* __restrict__ nWj_t,
         float* __restrict__ pi_out, float2* __restrict__ pjn_out) {
  // swizzle: b = xcd>>2; node-block u = (xcd&3)*524 + bi>>3 in [0,2096)
  int xcd = blockIdx.x & 7;
  int b = xcd >> 2;
  int u = (xcd & 3) * 524 + (blockIdx.x >> 3);
  int n = u * 4 + (threadIdx.x >> 6);
  int wid = b * NN + n;
  int lane = threadIdx.x & 63;
  int mt = cnt[wid];
  mt = mt < CAP ? mt : CAP;
  const float* hb = h_in + (size_t)b * NN * CC;
  const unsigned int* hmb = hm + (size_t)b * NN * (CC / 2) + lane;
  const float2* pjnb = pjn + b * NN;
  float p_i = pi[wid];
  float nd = normD[wid];
  const float2 hv = *(const float2*)(hb + (size_t)n * CC + lane * 2);
  float2 acc;
  if (INTRA) {
    // residual + self-loop message: h * (1 + tanh(pi+pj)/deg)  (fp32 path)
    float fac = 1.0f + tanhf(p_i + pjnb[n].x) * selfnorm[wid];
    acc.x = hv.x * fac;
    acc.y = hv.y * fac;
  } else {
    acc = hv;  // residual only
  }
  const int* cS = colS + (size_t)wid * CAP;
  for (int off = 0; off < mt; off += 64) {
    int rem = mt - off;
    int m = rem < 64 ? rem : 64;
    int src = 0;
    float c = 0.0f;
    if (lane < m) {
      src = cS[off + lane];
      float2 pn = pjnb[src];                 // one 8B random gather per edge
      float a = tanhf(p_i + pn.x);
      c = a * nd;
      if (INTRA) c *= pn.y;
    }
#pragma unroll
    for (int base = 0; base < 64; base += 16) {
      if (base >= m) break;
      unsigned int u16[16];
      float cj[16];
#pragma unroll
      for (int k = 0; k < 16; ++k) {
        int sj = __builtin_amdgcn_readlane(src, base + k);          // SGPR
        cj[k] = __int_as_float(
            __builtin_amdgcn_readlane(__float_as_int(c), base + k)); // SGPR
        u16[k] = hmb[sj * (CC / 2)];   // saddr-form load, 16 in flight
      }
#pragma unroll
      for (int k = 0; k < 16; ++k) {
        acc.x = fmaf(bf2f(u16[k] & 0xFFFFu), cj[k], acc.x);
        acc.y = fmaf(bf2f(u16[k] >> 16), cj[k], acc.y);
      }
    }
  }
  if (RELU) { acc.x = fmaxf(acc.x, 0.0f); acc.y = fmaxf(acc.y, 0.0f); }
  size_t oi = (size_t)wid * (CC / 2) + lane;
  *(float2*)(h_out + 2 * oi) = acc;
  if (NEXTPROJ) {
    hm_out[oi] = (f2bf_u(acc.y) << 16) | f2bf_u(acc.x);
    bool is_s = (n < NODE_NUM);
    const float* wi = is_s ? nWi_s : nWi_t;
    const float* wj = is_s ? nWj_s : nWj_t;
    float2 wiv = *(const float2*)(wi + lane * 2);
    float2 wjv = *(const float2*)(wj + lane * 2);
    float a = acc.x * wiv.x + acc.y * wiv.y;
    float c2 = acc.x * wjv.x + acc.y * wjv.y;
#pragma unroll
    for (int o = 32; o > 0; o >>= 1) {
      a += __shfl_xor(a, o, 64);
      c2 += __shfl_xor(c2, o, 64);
    }
    if (lane == 0) {
      pi_out[wid] = a;
      float2 pn;
      pn.x = c2;
      pn.y = NEXT_INTRA ? dinv_intra[wid] : 0.0f;
      pjn_out[wid] = pn;
    }
  }
}

extern "C" void kernel_launch(void* const* d_in, const int* in_sizes, int n_in,
                              void* d_out, int out_size, void* d_ws, size_t ws_size,
                              hipStream_t stream) {
  const float* x = (const float*)d_in[0];      // fp32 features [B,N,C]
  const int* ei = (const int*)d_in[1];         // int32 [B,2,E]
  const float* Wss = (const float*)d_in[2];    // fp32 [2, 2C]
  const float* Wtt = (const float*)d_in[3];
  const float* Wst = (const float*)d_in[4];
  const float* Wts = (const float*)d_in[5];
  float* out = (float*)d_out;                  // fp32 output [B,N,C]

  char* p = (char*)d_ws;
  auto alloc = [&](size_t bytes) {
    void* r = (void*)p;
    p += ((bytes + 255) & ~(size_t)255);
    return r;
  };
  float* h0 = (float*)alloc((size_t)BB * NN * CC * 4);
  float* h1 = (float*)alloc((size_t)BB * NN * CC * 4);
  unsigned int* xb = (unsigned int*)alloc((size_t)BB * NN * CC * 2);  // bf16 mirrors
  unsigned int* mb0 = (unsigned int*)alloc((size_t)BB * NN * CC * 2);
  unsigned int* mb1 = (unsigned int*)alloc((size_t)BB * NN * CC * 2);
  float* pi0 = (float*)alloc(BB * NN * 4);
  float* pi1 = (float*)alloc(BB * NN * 4);
  float2* pjn0 = (float2*)alloc(BB * NN * 8);   // paired {pj, src-norm}
  float2* pjn1 = (float2*)alloc(BB * NN * 8);
  float* dinv_intra = (float*)alloc(BB * NN * 4);
  float* selfnorm = (float*)alloc(BB * NN * 4);
  float* dinv_inter = (float*)alloc(BB * NN * 4);
  int* cur_intra = (int*)alloc(BB * NN * 4);
  int* cur_inter = (int*)alloc(BB * NN * 4);
  int* colS_intra = (int*)alloc((size_t)BB * NN * CAP * 4);  // 8.6 MB buckets
  int* colS_inter = (int*)alloc((size_t)BB * NN * CAP * 4);
  int* partCur = (int*)alloc(BB * P_B * 4);                  // 262 cursors
  unsigned int* partBuf = (unsigned int*)alloc((size_t)BB * P_B * CAPP * 4);  // 4.3 MB
  // total ws use: ~50 MB

  hipMemsetAsync(partCur, 0, BB * P_B * 4, stream);

  const int NODE_BLOCKS = (BB * NN * 64) / 256;  // 1 wave per node, 4 waves/block
  const float* wss0 = Wss, *wtt0 = Wtt, *wst0 = Wst, *wts0 = Wts;
  const float* wss1 = Wss + 256, *wtt1 = Wtt + 256, *wst1 = Wst + 256, *wts1 = Wts + 256;

  // phase 1 (edge partition) + init (pack x, layer-1 intra proj -> pi0/pjn0.x)
  k_part_init<<<FILLB + NODE_BLOCKS, 256, 0, stream>>>(
      ei, partCur, partBuf, x, xb, wss0, wss0 + 128, wtt0, wtt0 + 128, pi0, pjn0);
  // phase 2 (LDS bucket build, cnt-bounded dump, fused norms, pjn0.y)
  k_bucket<<<528, 256, 0, stream>>>(partCur, partBuf, cur_intra, cur_inter,
                                    colS_intra, colS_inter,
                                    dinv_intra, selfnorm, dinv_inter, pjn0);

  // layer 1 (intra, relu): (x,xb) -> (h0,mb0); fused proj for layer 2 (inter)
  // inter proj: s-node pi=W_ts[:C], pj=W_st[C:]; t-node pi=W_st[:C], pj=W_ts[C:]
  k_gather<true, true, true, false><<<NODE_BLOCKS, 256, 0, stream>>>(
      x, xb, h0, mb0, cur_intra, colS_intra, pi0, pjn0, dinv_intra, selfnorm, dinv_intra,
      wts0, wst0 + 128, wst0, wts0 + 128, pi1, pjn1);

  // layer 2 (inter, relu): (h0,mb0) -> (h1,mb1); fused proj for layer 3 (intra)
  k_gather<false, true, true, true><<<NODE_BLOCKS, 256, 0, stream>>>(
      h0, mb0, h1, mb1, cur_inter, colS_inter, pi1, pjn1, dinv_inter, selfnorm, dinv_intra,
      wss1, wss1 + 128, wtt1, wtt1 + 128, pi0, pjn0);

  // layer 3 (intra, relu): (h1,mb1) -> (h0,mb0); fused proj for layer 4 (inter)
  k_gather<true, true, true, false><<<NODE_BLOCKS, 256, 0, stream>>>(
      h1, mb1, h0, mb0, cur_intra, colS_intra, pi0, pjn0, dinv_intra, selfnorm, dinv_intra,
      wts1, wst1 + 128, wst1, wts1 + 128, pi1, pjn1);

  // layer 4 (inter, no relu): (h0,mb0) -> d_out; no next proj
  k_gather<false, false, false, false><<<NODE_BLOCKS, 256, 0, stream>>>(
      h0, mb0, out, nullptr, cur_inter, colS_inter, pi1, pjn1, dinv_inter, selfnorm,
      dinv_intra, nullptr, nullptr, nullptr, nullptr, nullptr, nullptr);
}